// Round 1
// 162.630 us; speedup vs baseline: 1.0055x; 1.0055x over previous
//
#include <hip/hip_runtime.h>

typedef short  s8v   __attribute__((ext_vector_type(8)));
typedef float  f32x4 __attribute__((ext_vector_type(4)));

#define SEQ 2048
#define WID 768

__device__ __forceinline__ unsigned fbits(float f) {
    union { float f; unsigned u; } v; v.f = f; return v.u;
}
__device__ __forceinline__ float bitsf(unsigned u) {
    union { unsigned u; float f; } v; v.u = u; return v.f;
}
__device__ __forceinline__ unsigned short f2b(float f) {
    unsigned u = fbits(f);
    return (unsigned short)((u + 0x7FFFu + ((u >> 16) & 1u)) >> 16);   // RNE
}
__device__ __forceinline__ unsigned packRNE(float a, float b) {
    unsigned ta = fbits(a) + 0x7FFFu + ((fbits(a) >> 16) & 1u);
    unsigned tb = fbits(b) + 0x7FFFu + ((fbits(b) >> 16) & 1u);
    return __builtin_amdgcn_perm(tb, ta, 0x07060302u);
}
__device__ __forceinline__ unsigned packTRUNC(float a, float b) {
    return __builtin_amdgcn_perm(fbits(b), fbits(a), 0x07060302u);
}
__device__ __forceinline__ f32x4 zero4() { f32x4 z = {0.f, 0.f, 0.f, 0.f}; return z; }

// async global->LDS DMA, 16B/lane; global ptr includes lane offset, LDS base wave-uniform
__device__ __forceinline__ void async16(const unsigned short* g, unsigned short* l) {
    __builtin_amdgcn_global_load_lds(
        (const __attribute__((address_space(1))) unsigned int*)g,
        (__attribute__((address_space(3))) unsigned int*)l, 16, 0, 0);
}

// ---------------------------------------------------------------------------
// convert: pure streaming.  blocks [0,6144): x -> XF bf16 A-frag-tiled
//   XF[((rowgrp*24 + kc32)*64 + l)*8 + j] = x[rowgrp*16 + (l&15)][kc32*32 + (l>>4)*8 + j]
// blocks [6144,6656): mask -> PM, SWAPPED layout for the new attn:
//   word at (gid=(qb,kb), lane=(quad,c)), bit (mt*16 + i*4 + nt) =
//     mask[qb*32 + mt*16 + c][kb*64 + quad*16 + i*4 + nt]
// blocks [6656,6728): W -> WF bf16 B-frag-tiled (unchanged)
// ---------------------------------------------------------------------------
__global__ __launch_bounds__(256) void convert_kernel(
    const float* __restrict__ x, const int* __restrict__ mask,
    const float* __restrict__ Wq, const float* __restrict__ Wk, const float* __restrict__ Wv,
    unsigned short* __restrict__ XF, unsigned short* __restrict__ WF,
    unsigned* __restrict__ PM)
{
    const int tid = threadIdx.x;
    const int blk = blockIdx.x;
    if (blk < 6144) {
        const unsigned s = blk * 256 + tid;            // 0 .. 1,572,863
        const unsigned g = s / 1536;
        const unsigned r = s - g * 1536;
        const unsigned kc32 = r >> 6, l = r & 63;
        const unsigned row = g * 16 + (l & 15);
        const unsigned k0 = kc32 * 32 + (l >> 4) * 8;
        float4 f0 = *(const float4*)&x[(size_t)row * WID + k0];
        float4 f1 = *(const float4*)&x[(size_t)row * WID + k0 + 4];
        uint4 w;
        w.x = packRNE(f0.x, f0.y); w.y = packRNE(f0.z, f0.w);
        w.z = packRNE(f1.x, f1.y); w.w = packRNE(f1.z, f1.w);
        *(uint4*)&XF[(size_t)s * 8] = w;
    } else if (blk < 6656) {
        const int b2 = blk - 6144;
        const int gid  = b2 * 4 + (tid >> 6);          // (qb32, kb)
        const int lane = tid & 63, quad = lane >> 4, c = lane & 15;
        const int qb = gid >> 5, kb = gid & 31;
        unsigned w = 0;
        #pragma unroll
        for (int mt = 0; mt < 2; ++mt) {
            const int q = qb * 32 + mt * 16 + c;
            #pragma unroll
            for (int i = 0; i < 4; ++i) {
                const int4 mm = *(const int4*)&mask[(size_t)q * SEQ + kb * 64 + quad * 16 + 4 * i];
                if (mm.x) w |= 1u << (mt * 16 + i * 4 + 0);
                if (mm.y) w |= 1u << (mt * 16 + i * 4 + 1);
                if (mm.z) w |= 1u << (mt * 16 + i * 4 + 2);
                if (mm.w) w |= 1u << (mt * 16 + i * 4 + 3);
            }
        }
        PM[(size_t)gid * 64 + lane] = w;
    } else {
        const int s2 = (blk - 6656) * 256 + tid;       // 0 .. 18431
        const int chunk = s2 >> 6, l = s2 & 63;
        const int ntg = chunk / 24, r = chunk - ntg * 24;
        const int kc = r >> 1, h = r & 1;
        const int mat = ntg >> 2;
        const int col = (ntg & 3) * 16 + (l & 15);
        const int k0 = kc * 64 + h * 32 + (l >> 4) * 8;
        const float* Wm = (mat == 0) ? Wq : (mat == 1) ? Wk : Wv;
        float p[8];
        #pragma unroll
        for (int j = 0; j < 8; ++j) p[j] = Wm[(size_t)(k0 + j) * 64 + col];
        uint4 w;
        w.x = packRNE(p[0], p[1]); w.y = packRNE(p[2], p[3]);
        w.z = packRNE(p[4], p[5]); w.w = packRNE(p[6], p[7]);
        *(uint4*)&WF[(size_t)s2 * 8] = w;
    }
}

// ---------------------------------------------------------------------------
// proj: m97-shaped bf16 GEMM [16384x768]x[768x192].  Unchanged except the VF
// epilogue key-permutation: V fragments now carry key = quad*16 + ks*8 + s
// (instead of ks*32 + quad*8 + s) so the attn PV MFMA can consume the
// register-resident P produced by the swapped QK^T with no cross-lane moves.
// (A and B agree on the permuted k-axis -> result is bitwise-equivalent GEMM.)
// ---------------------------------------------------------------------------
__global__ __launch_bounds__(512, 4) void qkv_proj_kernel(
    const unsigned short* __restrict__ XF, const unsigned short* __restrict__ WF,
    const float* __restrict__ bq, const float* __restrict__ bk, const float* __restrict__ bv,
    unsigned short* __restrict__ QF, unsigned short* __restrict__ KF,
    unsigned short* __restrict__ VF)
{
    __shared__ unsigned short AB[2][16384];   // per buf: A shorts [0,4096), B [4096,16384)
    unsigned short (*St)[200] = (unsigned short(*)[200])AB;   // epilogue overlay (25.6KB)

    const int tid = threadIdx.x;
    const int wv = tid >> 6, lane = tid & 63, quad = lane >> 4, c = lane & 15;
    const int rg = wv >> 2, cg = wv & 3;
    const int blk = blockIdx.x;
    const int g0 = blk * 4;                    // first rowgrp of block

    float bias[3];
    #pragma unroll
    for (int nt = 0; nt < 3; ++nt) {
        int col = cg * 48 + nt * 16 + c;
        const float* B = (col < 64) ? bq : (col < 128) ? bk : bv;
        bias[nt] = B[col & 63];
    }

    auto issue = [&](int kc, int b) {
        #pragma unroll
        for (int r = 0; r < 4; ++r) {
            const int d = wv * 4 + r;
            if (d < 8) {            // A chunk: rowgrp gl = d>>1, half h = d&1
                const int gl = d >> 1, h = d & 1;
                async16(XF + ((size_t)(g0 + gl) * 24 + 2 * kc + h) * 512 + lane * 8,
                        &AB[b][(gl * 2 + h) * 512]);
            } else {                // B chunk: ntg = (d-8)>>1, half h
                const int e = d - 8, ntg = e >> 1, h = e & 1;
                async16(WF + (((size_t)ntg * 12 + kc) * 2 + h) * 512 + lane * 8,
                        &AB[b][4096 + (ntg * 2 + h) * 512]);
            }
        }
    };

    f32x4 acc[2][3];
    #pragma unroll
    for (int mt = 0; mt < 2; ++mt)
        #pragma unroll
        for (int nt = 0; nt < 3; ++nt) acc[mt][nt] = zero4();

    issue(0, 0);
    for (int kc = 0; kc < 12; ++kc) {
        const int b = kc & 1;
        __syncthreads();                     // publish buf b (drain DMAs)
        if (kc < 11) issue(kc + 1, b ^ 1);   // overlapped with compute below

        s8v afr[2][2], bfr[3][2];
        #pragma unroll
        for (int mt = 0; mt < 2; ++mt)
            #pragma unroll
            for (int h = 0; h < 2; ++h)
                afr[mt][h] = *(const s8v*)&AB[b][((rg * 2 + mt) * 2 + h) * 512 + lane * 8];
        #pragma unroll
        for (int nt = 0; nt < 3; ++nt)
            #pragma unroll
            for (int h = 0; h < 2; ++h)
                bfr[nt][h] = *(const s8v*)&AB[b][4096 + ((cg * 3 + nt) * 2 + h) * 512 + lane * 8];
        #pragma unroll
        for (int h = 0; h < 2; ++h)
            #pragma unroll
            for (int mt = 0; mt < 2; ++mt)
                #pragma unroll
                for (int nt = 0; nt < 3; ++nt)
                    acc[mt][nt] = __builtin_amdgcn_mfma_f32_16x16x32_bf16(
                        afr[mt][h], bfr[nt][h], acc[mt][nt], 0, 0, 0);
        __syncthreads();                     // reads of buf b done
    }

    // ---- epilogue: bias + stage 64x192 bf16 tile (overlays AB[0])
    #pragma unroll
    for (int mt = 0; mt < 2; ++mt)
        #pragma unroll
        for (int nt = 0; nt < 3; ++nt)
            #pragma unroll
            for (int i = 0; i < 4; ++i)
                St[rg * 32 + mt * 16 + quad * 4 + i][cg * 48 + nt * 16 + c]
                    = f2b(acc[mt][nt][i] + bias[nt]);
    __syncthreads();

    {   // QF: rowgrp g = tid>>7, ks = (tid>>6)&1, frag lane l = tid&63
        const int g = tid >> 7, ks = (tid >> 6) & 1, l = tid & 63;
        uint4 v = *(uint4*)&St[g * 16 + (l & 15)][ks * 32 + (l >> 4) * 8];
        *(uint4*)&QF[(((size_t)(g0 + g)) * 2 + ks) * 512 + (size_t)l * 8] = v;
    }
    {   // KF: chunk ksnt = tid>>6 (ks = ksnt>>2, nt = ksnt&3), lane l
        const int ksnt = tid >> 6, l = tid & 63;
        const int ks = ksnt >> 2, nt = ksnt & 3;
        uint4 v = *(uint4*)&St[4 * (l & 15) + nt][64 + ks * 32 + (l >> 4) * 8];
        *(uint4*)&KF[(((size_t)blk * 8 + ksnt) * 64 + l) * 8] = v;
    }
    {   // VF: chunk ksnt, lane l: gather St columns (V transpose), permuted
        // key axis: lane (quad,c) holds keys quad*16 + ks*8 + s  (s=0..7)
        const int ksnt = tid >> 6, l = tid & 63;
        const int ks = ksnt >> 2, nt = ksnt & 3;
        const int d = 128 + nt * 16 + (l & 15);
        const int r0 = (l >> 4) * 16 + ks * 8;
        unsigned short p[8];
        #pragma unroll
        for (int s = 0; s < 8; ++s) p[s] = St[r0 + s][d];
        uint4 w;
        w.x = (unsigned)p[0] | ((unsigned)p[1] << 16);
        w.y = (unsigned)p[2] | ((unsigned)p[3] << 16);
        w.z = (unsigned)p[4] | ((unsigned)p[5] << 16);
        w.w = (unsigned)p[6] | ((unsigned)p[7] << 16);
        *(uint4*)&VF[(((size_t)blk * 8 + ksnt) * 64 + l) * 8] = w;
    }
}

// ---------------------------------------------------------------------------
// attn: flash attention, MFMA bf16, fixed-shift softmax (same math as the
// verified R8 kernel).  R9 changes:
//   * swapped QK^T  (S^T = mfma(K, Q)): lane (quad,c) holds S[q=c][key=
//     16*quad + 4*i + nt] -> P stays entirely in registers; combined with the
//     permuted-key VF layout, P feeds the PV MFMA A-operand directly.
//     The Ps LDS buffer (36KB) and its write/read round trip are GONE.
//   * KV double-buffered (128KB LDS) with raw s_barrier + counted
//     s_waitcnt vmcnt(4) (never 0 mid-loop, T3+T4): DMA for tile t+2 issued
//     at the bottom of t -> one full iteration of latency slack; no more
//     per-iteration vmcnt(0) drain.
//   * PM words (8) preloaded into VGPRs pre-loop (asm-pinned) so in-loop
//     vmcnt counts only this wave's 4 KV DMAs per tile.
// ---------------------------------------------------------------------------
__global__ __launch_bounds__(1024, 4) void attn_kernel(
    const unsigned short* __restrict__ QF, const unsigned short* __restrict__ KF,
    const unsigned short* __restrict__ VF, const unsigned* __restrict__ PM,
    float* __restrict__ out)
{
    __shared__ unsigned short KV[4][2][8192];  // per slice, per buf: K [0,4096), V [4096,8192)
    __shared__ float Obuf[64][68];             // 17.4KB merge buffer
    __shared__ float Lbuf[64];

    const int tid = threadIdx.x;
    const int wv = tid >> 6, lane = tid & 63, quad = lane >> 4, c = lane & 15;
    const int sl = wv & 3, qg = wv >> 2, mt = qg & 1;
    const int blk = blockIdx.x;
    const int bb = blk & 7, qt = blk >> 3;
    const size_t qrow0 = (size_t)bb * SEQ + qt * 64;

    if (tid < 64) Lbuf[tid] = 0.f;

    // ---- preload all 8 PM words (one per kt) + Q frags, then pin their
    //      waits BEFORE any DMA so in-loop vmcnt counts only KV DMAs.
    unsigned pm[8];
    #pragma unroll
    for (int kt = 0; kt < 8; ++kt)
        pm[kt] = PM[(size_t)(((qt * 2 + (qg >> 1)) * 32 + sl * 8 + kt) * 64 + lane)];

    union Q8 { s8v v; unsigned w[4]; } qf[2];
    {
        const size_t qgrp = (size_t)bb * 128 + qt * 4 + qg;
        #pragma unroll
        for (int ks = 0; ks < 2; ++ks)
            qf[ks].v = *(const s8v*)&QF[(qgrp * 2 + ks) * 512 + (size_t)lane * 8];
    }
    asm volatile("s_waitcnt vmcnt(0)" ::: "memory");
    #pragma unroll
    for (int kt = 0; kt < 8; ++kt) asm volatile("" : "+v"(pm[kt]));
    #pragma unroll
    for (int ks = 0; ks < 2; ++ks)
        #pragma unroll
        for (int j = 0; j < 4; ++j) asm volatile("" : "+v"(qf[ks].w[j]));
    __builtin_amdgcn_sched_barrier(0);

    f32x4 O[4];
    float lro = 0.f;
    #pragma unroll
    for (int nt = 0; nt < 4; ++nt) O[nt] = zero4();

    // KV DMA for tile kt of this wave's slice into buffer b (4 chunks/wave)
    auto kv_dma = [&](int kt, int b) {
        const size_t kbg = (size_t)bb * 32 + sl * 8 + kt;
        #pragma unroll
        for (int r = 0; r < 4; ++r) {
            const int d = qg * 4 + r;
            const unsigned short* src = (d < 8)
                ? KF + kbg * 4096 + (d & 7) * 512 + lane * 8
                : VF + kbg * 4096 + (d & 7) * 512 + lane * 8;
            async16(src, &KV[sl][b][(d >> 3) * 4096 + (d & 7) * 512]);
        }
    };

    kv_dma(0, 0);
    kv_dma(1, 1);

    #pragma unroll
    for (int kt = 0; kt < 8; ++kt) {
        const int b = kt & 1;
        // tile kt's 4 DMAs are the oldest outstanding; tile kt+1's 4 may fly on
        if (kt < 7) asm volatile("s_waitcnt vmcnt(4)" ::: "memory");
        else        asm volatile("s_waitcnt vmcnt(0)" ::: "memory");
        __builtin_amdgcn_sched_barrier(0);
        __builtin_amdgcn_s_barrier();              // KV[sl][b] published

        // ---- S^T = K Q^T : lane (quad,c) gets S[q=c][key = 16*quad + 4*i + nt]
        f32x4 S[4];
        #pragma unroll
        for (int nt = 0; nt < 4; ++nt) S[nt] = zero4();
        #pragma unroll
        for (int ks = 0; ks < 2; ++ks) {
            s8v kfr[4];
            #pragma unroll
            for (int nt = 0; nt < 4; ++nt)
                kfr[nt] = *(const s8v*)&KV[sl][b][((ks * 4 + nt) * 64 + lane) * 8];
            #pragma unroll
            for (int nt = 0; nt < 4; ++nt)
                S[nt] = __builtin_amdgcn_mfma_f32_16x16x32_bf16(kfr[nt], qf[ks].v, S[nt], 0, 0, 0);
        }

        // ---- fixed-shift softmax in registers: p = 2^(s*0.125/ln2 - 15/ln2)
        const unsigned pmh = pm[kt] >> (mt * 16);
        float p[4][4];                              // p[nt][i] = key 16*quad+4*i+nt
        #pragma unroll
        for (int i = 0; i < 4; ++i)
            #pragma unroll
            for (int nt = 0; nt < 4; ++nt) {
                float e = exp2f(fmaf(S[nt][i], 0.18033688011112042f, -21.640425613334451f));
                p[nt][i] = ((pmh >> (i * 4 + nt)) & 1u) ? e : 0.f;
            }
        union { unsigned w[8]; s8v v[2]; } P;       // shorts = keys 16*quad+0..15
        #pragma unroll
        for (int j = 0; j < 8; ++j) {
            unsigned uu = packTRUNC(p[2 * (j & 1)][j >> 1], p[2 * (j & 1) + 1][j >> 1]);
            P.w[j] = uu;
            lro += bitsf(uu << 16) + bitsf(uu & 0xFFFF0000u);
        }

        // ---- O += P V  (permuted key axis: slot (ks,quad,j) == key 16q+8ks+j
        //      on BOTH operands -> plain register A-frags, no shuffles)
        #pragma unroll
        for (int ks = 0; ks < 2; ++ks) {
            s8v vfr[4];
            #pragma unroll
            for (int nt = 0; nt < 4; ++nt)
                vfr[nt] = *(const s8v*)&KV[sl][b][4096 + ((ks * 4 + nt) * 64 + lane) * 8];
            #pragma unroll
            for (int nt = 0; nt < 4; ++nt)
                O[nt] = __builtin_amdgcn_mfma_f32_16x16x32_bf16(P.v[ks], vfr[nt], O[nt], 0, 0, 0);
        }

        if (kt < 6) {
            __builtin_amdgcn_s_barrier();          // all reads of buf b done
            kv_dma(kt + 2, b);                     // full iteration of slack
        }
    }

    // ---- merge 4 slices per q-group
    #pragma unroll
    for (int j = 0; j < 5; ++j) {
        int idx = tid + 1024 * j;
        if (idx < 64 * 68) ((float*)Obuf)[idx] = 0.f;
    }
    __syncthreads();

    {   // row-sum: lane (quad,c) holds partial for q=c over its 16-key strips
        float l = lro;
        l += __shfl_xor(l, 16);
        l += __shfl_xor(l, 32);
        if (quad == 0) atomicAdd(&Lbuf[qg * 16 + c], l);
    }
    #pragma unroll
    for (int i = 0; i < 4; ++i)
        #pragma unroll
        for (int nt = 0; nt < 4; ++nt)
            atomicAdd(&Obuf[qg * 16 + quad * 4 + i][nt * 16 + c], O[nt][i]);
    __syncthreads();
    {
        const int r = tid >> 4, d4 = (tid & 15) * 4;
        const float invL = 1.0f / Lbuf[r];
        float4 v = *(float4*)&Obuf[r][d4];
        float4 o = make_float4(v.x * invL, v.y * invL, v.z * invL, v.w * invL);
        *(float4*)&out[(qrow0 + r) * 64 + d4] = o;
    }
}

extern "C" void kernel_launch(void* const* d_in, const int* in_sizes, int n_in,
                              void* d_out, int out_size, void* d_ws, size_t ws_size,
                              hipStream_t stream)
{
    const float* x    = (const float*)d_in[0];
    const float* Wq   = (const float*)d_in[1];
    const float* bq   = (const float*)d_in[2];
    const float* Wk   = (const float*)d_in[3];
    const float* bk   = (const float*)d_in[4];
    const float* Wv   = (const float*)d_in[5];
    const float* bv   = (const float*)d_in[6];
    const int*   mask = (const int*)d_in[7];
    float* out = (float*)d_out;

    // ws: QF/KF/VF 2MB each + XF 24MB + WF 288KB + PM 512KB ≈ 31 MB
    unsigned short* QF = (unsigned short*)d_ws;
    unsigned short* KF = QF + (size_t)16384 * 64;
    unsigned short* VF = KF + (size_t)16384 * 64;
    unsigned short* XF = VF + (size_t)16384 * 64;
    unsigned short* WF = XF + (size_t)16384 * WID;
    unsigned*       PM = (unsigned*)(WF + (size_t)192 * WID);

    convert_kernel<<<6728, 256, 0, stream>>>(x, mask, Wq, Wk, Wv, XF, WF, PM);
    qkv_proj_kernel<<<256, 512, 0, stream>>>(XF, WF, bq, bk, bv, QF, KF, VF);
    attn_kernel<<<256, 1024, 0, stream>>>(QF, KF, VF, PM, out);
}

// Round 2
// 159.477 us; speedup vs baseline: 1.0254x; 1.0198x over previous
//
#include <hip/hip_runtime.h>

typedef short  s8v   __attribute__((ext_vector_type(8)));
typedef float  f32x4 __attribute__((ext_vector_type(4)));

#define SEQ 2048
#define WID 768

__device__ __forceinline__ unsigned fbits(float f) {
    union { float f; unsigned u; } v; v.f = f; return v.u;
}
__device__ __forceinline__ float bitsf(unsigned u) {
    union { unsigned u; float f; } v; v.u = u; return v.f;
}
__device__ __forceinline__ unsigned short f2b(float f) {
    unsigned u = fbits(f);
    return (unsigned short)((u + 0x7FFFu + ((u >> 16) & 1u)) >> 16);   // RNE
}
__device__ __forceinline__ unsigned packRNE(float a, float b) {
    unsigned ta = fbits(a) + 0x7FFFu + ((fbits(a) >> 16) & 1u);
    unsigned tb = fbits(b) + 0x7FFFu + ((fbits(b) >> 16) & 1u);
    return __builtin_amdgcn_perm(tb, ta, 0x07060302u);
}
__device__ __forceinline__ unsigned packTRUNC(float a, float b) {
    return __builtin_amdgcn_perm(fbits(b), fbits(a), 0x07060302u);
}
__device__ __forceinline__ f32x4 zero4() { f32x4 z = {0.f, 0.f, 0.f, 0.f}; return z; }

// async global->LDS DMA, 16B/lane; global ptr includes lane offset, LDS base wave-uniform
__device__ __forceinline__ void async16(const unsigned short* g, unsigned short* l) {
    __builtin_amdgcn_global_load_lds(
        (const __attribute__((address_space(1))) unsigned int*)g,
        (__attribute__((address_space(3))) unsigned int*)l, 16, 0, 0);
}

// ---------------------------------------------------------------------------
// convert v2: x->XF section ELIMINATED (fused into proj).  584 blocks:
// blocks [0,512): mask -> PM, swapped layout (verified R9):
//   word at (gid=(qb,kb), lane=(quad,c)), bit (mt*16 + i*4 + nt) =
//     mask[qb*32 + mt*16 + c][kb*64 + quad*16 + i*4 + nt]
// blocks [512,584): W -> WF bf16 B-frag-tiled (unchanged logic)
// ---------------------------------------------------------------------------
__global__ __launch_bounds__(256) void convert_kernel(
    const int* __restrict__ mask,
    const float* __restrict__ Wq, const float* __restrict__ Wk, const float* __restrict__ Wv,
    unsigned short* __restrict__ WF, unsigned* __restrict__ PM)
{
    const int tid = threadIdx.x;
    const int blk = blockIdx.x;
    if (blk < 512) {
        const int gid  = blk * 4 + (tid >> 6);         // (qb32, kb)
        const int lane = tid & 63, quad = lane >> 4, c = lane & 15;
        const int qb = gid >> 5, kb = gid & 31;
        unsigned w = 0;
        #pragma unroll
        for (int mt = 0; mt < 2; ++mt) {
            const int q = qb * 32 + mt * 16 + c;
            #pragma unroll
            for (int i = 0; i < 4; ++i) {
                const int4 mm = *(const int4*)&mask[(size_t)q * SEQ + kb * 64 + quad * 16 + 4 * i];
                if (mm.x) w |= 1u << (mt * 16 + i * 4 + 0);
                if (mm.y) w |= 1u << (mt * 16 + i * 4 + 1);
                if (mm.z) w |= 1u << (mt * 16 + i * 4 + 2);
                if (mm.w) w |= 1u << (mt * 16 + i * 4 + 3);
            }
        }
        PM[(size_t)gid * 64 + lane] = w;
    } else {
        const int s2 = (blk - 512) * 256 + tid;        // 0 .. 18431
        const int chunk = s2 >> 6, l = s2 & 63;
        const int ntg = chunk / 24, r = chunk - ntg * 24;
        const int kc = r >> 1, h = r & 1;
        const int mat = ntg >> 2;
        const int col = (ntg & 3) * 16 + (l & 15);
        const int k0 = kc * 64 + h * 32 + (l >> 4) * 8;
        const float* Wm = (mat == 0) ? Wq : (mat == 1) ? Wk : Wv;
        float p[8];
        #pragma unroll
        for (int j = 0; j < 8; ++j) p[j] = Wm[(size_t)(k0 + j) * 64 + col];
        uint4 w;
        w.x = packRNE(p[0], p[1]); w.y = packRNE(p[2], p[3]);
        w.z = packRNE(p[4], p[5]); w.w = packRNE(p[6], p[7]);
        *(uint4*)&WF[(size_t)s2 * 8] = w;
    }
}

// ---------------------------------------------------------------------------
// proj v2: bf16 GEMM [16384x768]x[768x192] with A-conversion FUSED IN.
// Reads x (f32) directly: per iter each thread loads 32B of x, packs to 8
// bf16 (identical RNE code as old convert -> bit-identical LDS image), and
// ds_writes its 16B frag chunk; B (WF) still DMA'd via global_load_lds.
// Single barrier per K-iteration: sync publishes buf b; staging of kc+1
// (x-reg prefetch + B DMA issue, pack+ds_write after compute) targets b^1
// whose readers finished before this sync.  The XF intermediate (48MB of
// HBM round-trip) is gone.
// ---------------------------------------------------------------------------
__global__ __launch_bounds__(512, 4) void qkv_proj_kernel(
    const float* __restrict__ x, const unsigned short* __restrict__ WF,
    const float* __restrict__ bq, const float* __restrict__ bk, const float* __restrict__ bv,
    unsigned short* __restrict__ QF, unsigned short* __restrict__ KF,
    unsigned short* __restrict__ VF)
{
    __shared__ unsigned short AB[2][16384];   // per buf: A shorts [0,4096), B [4096,16384)
    unsigned short (*St)[200] = (unsigned short(*)[200])AB;   // epilogue overlay (25.6KB, buf0)

    const int tid = threadIdx.x;
    const int wv = tid >> 6, lane = tid & 63, quad = lane >> 4, c = lane & 15;
    const int rg = wv >> 2, cg = wv & 3;
    const int blk = blockIdx.x;
    const int g0 = blk * 4;                    // first rowgrp of block

    float bias[3];
    #pragma unroll
    for (int nt = 0; nt < 3; ++nt) {
        int col = cg * 48 + nt * 16 + c;
        const float* B = (col < 64) ? bq : (col < 128) ? bk : bv;
        bias[nt] = B[col & 63];
    }

    // A staging geometry: thread -> chunk (gl,h), frag lane l.  LDS word
    // tid*8 == chunk*512 + l*8, matching the old XF-DMA destination exactly.
    const int chunk = tid >> 6;                // 0..7
    const int gl = chunk >> 1, hh = chunk & 1;
    const int arow = (g0 + gl) * 16 + (lane & 15);
    const float* xrow = x + (size_t)arow * WID + hh * 32 + ((lane >> 4) & 3) * 8;

    auto issueB = [&](int kc, int b) {
        #pragma unroll
        for (int r = 0; r < 3; ++r) {
            const int e = wv * 3 + r;          // 0..23: ntg = e>>1, half h
            const int ntg = e >> 1, h = e & 1;
            async16(WF + (((size_t)ntg * 12 + kc) * 2 + h) * 512 + lane * 8,
                    &AB[b][4096 + (ntg * 2 + h) * 512]);
        }
    };
    auto stageA_write = [&](int b, float4 f0, float4 f1) {
        uint4 w;
        w.x = packRNE(f0.x, f0.y); w.y = packRNE(f0.z, f0.w);
        w.z = packRNE(f1.x, f1.y); w.w = packRNE(f1.z, f1.w);
        *(uint4*)&AB[b][(size_t)tid * 8] = w;
    };

    f32x4 acc[2][3];
    #pragma unroll
    for (int mt = 0; mt < 2; ++mt)
        #pragma unroll
        for (int nt = 0; nt < 3; ++nt) acc[mt][nt] = zero4();

    {   // prologue: stage A(0) -> buf0, issue B(0) -> buf0
        float4 f0 = *(const float4*)&xrow[0];
        float4 f1 = *(const float4*)&xrow[4];
        stageA_write(0, f0, f1);
        issueB(0, 0);
    }

    for (int kc = 0; kc < 12; ++kc) {
        const int b = kc & 1;
        __syncthreads();   // publish buf b (B-DMA vmcnt + A ds_writes); b^1 readers done
        float4 f0, f1;
        if (kc < 11) {
            f0 = *(const float4*)&xrow[(kc + 1) * 64];
            f1 = *(const float4*)&xrow[(kc + 1) * 64 + 4];
            issueB(kc + 1, b ^ 1);
        }

        s8v afr[2][2], bfr[3][2];
        #pragma unroll
        for (int mt = 0; mt < 2; ++mt)
            #pragma unroll
            for (int h = 0; h < 2; ++h)
                afr[mt][h] = *(const s8v*)&AB[b][((rg * 2 + mt) * 2 + h) * 512 + lane * 8];
        #pragma unroll
        for (int nt = 0; nt < 3; ++nt)
            #pragma unroll
            for (int h = 0; h < 2; ++h)
                bfr[nt][h] = *(const s8v*)&AB[b][4096 + ((cg * 3 + nt) * 2 + h) * 512 + lane * 8];
        #pragma unroll
        for (int h = 0; h < 2; ++h)
            #pragma unroll
            for (int mt = 0; mt < 2; ++mt)
                #pragma unroll
                for (int nt = 0; nt < 3; ++nt)
                    acc[mt][nt] = __builtin_amdgcn_mfma_f32_16x16x32_bf16(
                        afr[mt][h], bfr[nt][h], acc[mt][nt], 0, 0, 0);

        if (kc < 11) stageA_write(b ^ 1, f0, f1);
    }

    // ---- epilogue: bias + stage 64x192 bf16 tile (overlays buf0; last
    // compute read buf1, so no sync needed before the St writes)
    #pragma unroll
    for (int mt = 0; mt < 2; ++mt)
        #pragma unroll
        for (int nt = 0; nt < 3; ++nt)
            #pragma unroll
            for (int i = 0; i < 4; ++i)
                St[rg * 32 + mt * 16 + quad * 4 + i][cg * 48 + nt * 16 + c]
                    = f2b(acc[mt][nt][i] + bias[nt]);
    __syncthreads();

    {   // QF: rowgrp g = tid>>7, ks = (tid>>6)&1, frag lane l = tid&63
        const int g = tid >> 7, ks = (tid >> 6) & 1, l = tid & 63;
        uint4 v = *(uint4*)&St[g * 16 + (l & 15)][ks * 32 + (l >> 4) * 8];
        *(uint4*)&QF[(((size_t)(g0 + g)) * 2 + ks) * 512 + (size_t)l * 8] = v;
    }
    {   // KF: chunk ksnt = tid>>6 (ks = ksnt>>2, nt = ksnt&3), lane l
        const int ksnt = tid >> 6, l = tid & 63;
        const int ks = ksnt >> 2, nt = ksnt & 3;
        uint4 v = *(uint4*)&St[4 * (l & 15) + nt][64 + ks * 32 + (l >> 4) * 8];
        *(uint4*)&KF[(((size_t)blk * 8 + ksnt) * 64 + l) * 8] = v;
    }
    {   // VF: chunk ksnt, lane l: gather St columns (V transpose), permuted
        // key axis: lane (quad,c) holds keys quad*16 + ks*8 + s  (s=0..7)
        const int ksnt = tid >> 6, l = tid & 63;
        const int ks = ksnt >> 2, nt = ksnt & 3;
        const int d = 128 + nt * 16 + (l & 15);
        const int r0 = (l >> 4) * 16 + ks * 8;
        unsigned short p[8];
        #pragma unroll
        for (int s = 0; s < 8; ++s) p[s] = St[r0 + s][d];
        uint4 w;
        w.x = (unsigned)p[0] | ((unsigned)p[1] << 16);
        w.y = (unsigned)p[2] | ((unsigned)p[3] << 16);
        w.z = (unsigned)p[4] | ((unsigned)p[5] << 16);
        w.w = (unsigned)p[6] | ((unsigned)p[7] << 16);
        *(uint4*)&VF[(((size_t)blk * 8 + ksnt) * 64 + l) * 8] = w;
    }
}

// ---------------------------------------------------------------------------
// attn: byte-identical to verified R9 kernel (swapped QK^T, register P,
// KV double-buffer with counted vmcnt).
// ---------------------------------------------------------------------------
__global__ __launch_bounds__(1024, 4) void attn_kernel(
    const unsigned short* __restrict__ QF, const unsigned short* __restrict__ KF,
    const unsigned short* __restrict__ VF, const unsigned* __restrict__ PM,
    float* __restrict__ out)
{
    __shared__ unsigned short KV[4][2][8192];  // per slice, per buf: K [0,4096), V [4096,8192)
    __shared__ float Obuf[64][68];             // 17.4KB merge buffer
    __shared__ float Lbuf[64];

    const int tid = threadIdx.x;
    const int wv = tid >> 6, lane = tid & 63, quad = lane >> 4, c = lane & 15;
    const int sl = wv & 3, qg = wv >> 2, mt = qg & 1;
    const int blk = blockIdx.x;
    const int bb = blk & 7, qt = blk >> 3;
    const size_t qrow0 = (size_t)bb * SEQ + qt * 64;

    if (tid < 64) Lbuf[tid] = 0.f;

    unsigned pm[8];
    #pragma unroll
    for (int kt = 0; kt < 8; ++kt)
        pm[kt] = PM[(size_t)(((qt * 2 + (qg >> 1)) * 32 + sl * 8 + kt) * 64 + lane)];

    union Q8 { s8v v; unsigned w[4]; } qf[2];
    {
        const size_t qgrp = (size_t)bb * 128 + qt * 4 + qg;
        #pragma unroll
        for (int ks = 0; ks < 2; ++ks)
            qf[ks].v = *(const s8v*)&QF[(qgrp * 2 + ks) * 512 + (size_t)lane * 8];
    }
    asm volatile("s_waitcnt vmcnt(0)" ::: "memory");
    #pragma unroll
    for (int kt = 0; kt < 8; ++kt) asm volatile("" : "+v"(pm[kt]));
    #pragma unroll
    for (int ks = 0; ks < 2; ++ks)
        #pragma unroll
        for (int j = 0; j < 4; ++j) asm volatile("" : "+v"(qf[ks].w[j]));
    __builtin_amdgcn_sched_barrier(0);

    f32x4 O[4];
    float lro = 0.f;
    #pragma unroll
    for (int nt = 0; nt < 4; ++nt) O[nt] = zero4();

    auto kv_dma = [&](int kt, int b) {
        const size_t kbg = (size_t)bb * 32 + sl * 8 + kt;
        #pragma unroll
        for (int r = 0; r < 4; ++r) {
            const int d = qg * 4 + r;
            const unsigned short* src = (d < 8)
                ? KF + kbg * 4096 + (d & 7) * 512 + lane * 8
                : VF + kbg * 4096 + (d & 7) * 512 + lane * 8;
            async16(src, &KV[sl][b][(d >> 3) * 4096 + (d & 7) * 512]);
        }
    };

    kv_dma(0, 0);
    kv_dma(1, 1);

    #pragma unroll
    for (int kt = 0; kt < 8; ++kt) {
        const int b = kt & 1;
        if (kt < 7) asm volatile("s_waitcnt vmcnt(4)" ::: "memory");
        else        asm volatile("s_waitcnt vmcnt(0)" ::: "memory");
        __builtin_amdgcn_sched_barrier(0);
        __builtin_amdgcn_s_barrier();              // KV[sl][b] published

        f32x4 S[4];
        #pragma unroll
        for (int nt = 0; nt < 4; ++nt) S[nt] = zero4();
        #pragma unroll
        for (int ks = 0; ks < 2; ++ks) {
            s8v kfr[4];
            #pragma unroll
            for (int nt = 0; nt < 4; ++nt)
                kfr[nt] = *(const s8v*)&KV[sl][b][((ks * 4 + nt) * 64 + lane) * 8];
            #pragma unroll
            for (int nt = 0; nt < 4; ++nt)
                S[nt] = __builtin_amdgcn_mfma_f32_16x16x32_bf16(kfr[nt], qf[ks].v, S[nt], 0, 0, 0);
        }

        const unsigned pmh = pm[kt] >> (mt * 16);
        float p[4][4];
        #pragma unroll
        for (int i = 0; i < 4; ++i)
            #pragma unroll
            for (int nt = 0; nt < 4; ++nt) {
                float e = exp2f(fmaf(S[nt][i], 0.18033688011112042f, -21.640425613334451f));
                p[nt][i] = ((pmh >> (i * 4 + nt)) & 1u) ? e : 0.f;
            }
        union { unsigned w[8]; s8v v[2]; } P;
        #pragma unroll
        for (int j = 0; j < 8; ++j) {
            unsigned uu = packTRUNC(p[2 * (j & 1)][j >> 1], p[2 * (j & 1) + 1][j >> 1]);
            P.w[j] = uu;
            lro += bitsf(uu << 16) + bitsf(uu & 0xFFFF0000u);
        }

        #pragma unroll
        for (int ks = 0; ks < 2; ++ks) {
            s8v vfr[4];
            #pragma unroll
            for (int nt = 0; nt < 4; ++nt)
                vfr[nt] = *(const s8v*)&KV[sl][b][4096 + ((ks * 4 + nt) * 64 + lane) * 8];
            #pragma unroll
            for (int nt = 0; nt < 4; ++nt)
                O[nt] = __builtin_amdgcn_mfma_f32_16x16x32_bf16(P.v[ks], vfr[nt], O[nt], 0, 0, 0);
        }

        if (kt < 6) {
            __builtin_amdgcn_s_barrier();          // all reads of buf b done
            kv_dma(kt + 2, b);
        }
    }

    #pragma unroll
    for (int j = 0; j < 5; ++j) {
        int idx = tid + 1024 * j;
        if (idx < 64 * 68) ((float*)Obuf)[idx] = 0.f;
    }
    __syncthreads();

    {
        float l = lro;
        l += __shfl_xor(l, 16);
        l += __shfl_xor(l, 32);
        if (quad == 0) atomicAdd(&Lbuf[qg * 16 + c], l);
    }
    #pragma unroll
    for (int i = 0; i < 4; ++i)
        #pragma unroll
        for (int nt = 0; nt < 4; ++nt)
            atomicAdd(&Obuf[qg * 16 + quad * 4 + i][nt * 16 + c], O[nt][i]);
    __syncthreads();
    {
        const int r = tid >> 4, d4 = (tid & 15) * 4;
        const float invL = 1.0f / Lbuf[r];
        float4 v = *(float4*)&Obuf[r][d4];
        float4 o = make_float4(v.x * invL, v.y * invL, v.z * invL, v.w * invL);
        *(float4*)&out[(qrow0 + r) * 64 + d4] = o;
    }
}

extern "C" void kernel_launch(void* const* d_in, const int* in_sizes, int n_in,
                              void* d_out, int out_size, void* d_ws, size_t ws_size,
                              hipStream_t stream)
{
    const float* x    = (const float*)d_in[0];
    const float* Wq   = (const float*)d_in[1];
    const float* bq   = (const float*)d_in[2];
    const float* Wk   = (const float*)d_in[3];
    const float* bk   = (const float*)d_in[4];
    const float* Wv   = (const float*)d_in[5];
    const float* bv   = (const float*)d_in[6];
    const int*   mask = (const int*)d_in[7];
    float* out = (float*)d_out;

    // ws: QF/KF/VF 2MB each + WF 288KB + PM 512KB  (XF eliminated)
    unsigned short* QF = (unsigned short*)d_ws;
    unsigned short* KF = QF + (size_t)16384 * 64;
    unsigned short* VF = KF + (size_t)16384 * 64;
    unsigned short* WF = VF + (size_t)16384 * 64;
    unsigned*       PM = (unsigned*)(WF + (size_t)192 * WID);

    convert_kernel<<<584, 256, 0, stream>>>(mask, Wq, Wk, Wv, WF, PM);
    qkv_proj_kernel<<<256, 512, 0, stream>>>(x, WF, bq, bk, bv, QF, KF, VF);
    attn_kernel<<<256, 1024, 0, stream>>>(QF, KF, VF, PM, out);
}